// Round 11
// baseline (459.902 us; speedup 1.0000x reference)
//
#include <hip/hip_runtime.h>
#include <hip/hip_bf16.h>

// Problem constants (from setup_inputs: x = [2, 1024, 64] fp32)
constexpr int BB = 2;
constexpr int N  = 1024;
constexpr int C  = 64;
constexpr int S  = N * N;          // 1048576 = 2^20
constexpr int KSEL = S / 6;        // 174762 entries set to 1 per batch
constexpr int EQCAP = 1 << 17;     // exact-tie capacity per batch

typedef double d4 __attribute__((ext_vector_type(4)));

// Order-preserving uint64 mapping of fp64 (monotone: a<b <=> key(a)<key(b))
__device__ __forceinline__ unsigned long long d2key(double d) {
    unsigned long long u = (unsigned long long)__double_as_longlong(d);
    return (u & 0x8000000000000000ULL) ? ~u : (u | 0x8000000000000000ULL);
}

__device__ __forceinline__ void astore64(unsigned long long* p, unsigned long long v) {
    (void)__hip_atomic_exchange(p, v, __ATOMIC_RELAXED, __HIP_MEMORY_SCOPE_AGENT);
}

// Two-level scan over an nbins histogram (cs = nbins/256 per thread): find the
// largest bucket s.t. count of entries in buckets >= it reaches kneed.
// Block-uniform; reusable sequentially (trailing barrier).
__device__ __forceinline__ void walk_level(const unsigned int* __restrict__ g, int cs,
                                           unsigned int kneed_in,
                                           unsigned int& bucket, unsigned int& kneed_out) {
    __shared__ unsigned int chunks[256];
    __shared__ unsigned int res[2];
    int t = threadIdx.x;
    unsigned int s = 0;
    for (int i = 0; i < cs; ++i) s += g[t * cs + i];
    chunks[t] = s;
    __syncthreads();
    if (t == 0) {
        unsigned int cum = 0; int Cc_ = 0;
        for (int ch = 255; ch >= 0; --ch) {
            if (cum + chunks[ch] >= kneed_in) { Cc_ = ch; break; }
            cum += chunks[ch];
        }
        unsigned int bkt = 0, kn = 1;
        for (int i = cs - 1; i >= 0; --i) {
            unsigned int h = g[Cc_ * cs + i];
            if (cum + h >= kneed_in) { bkt = (unsigned int)(Cc_ * cs + i); kn = kneed_in - cum; break; }
            cum += h;
        }
        res[0] = bkt; res[1] = kn;
    }
    __syncthreads();
    bucket = res[0]; kneed_out = res[1];
    __syncthreads();
}

// ---------------------------------------------------------------------------
// K1: pairwise adjacencies with fused per-row stats. 64x64 tile (512 wgs).
__global__ __launch_bounds__(256) void k_pairwise(const float* __restrict__ x,
                                                  double* __restrict__ E,
                                                  double* __restrict__ Ch,
                                                  double* __restrict__ Cc) {
    int b  = blockIdx.z;
    int i0 = blockIdx.y * 64;
    int j0 = blockIdx.x * 64;
    __shared__ double xi[64][65];
    __shared__ double xj[64][65];
    __shared__ double mi[64], ri_[64], si[64];
    __shared__ double mj[64], rj_[64], sj[64];

    int t  = threadIdx.x;
    int r  = t >> 2;
    int cb = (t & 3) * 16;
    const float* xb = x + (size_t)b * N * C;
    {
        const float4* pi = (const float4*)(xb + (size_t)(i0 + r) * C + cb);
        const float4* pj = (const float4*)(xb + (size_t)(j0 + r) * C + cb);
#pragma unroll
        for (int m4 = 0; m4 < 4; ++m4) {
            float4 fi = pi[m4], fj = pj[m4];
            xi[r][cb + 4 * m4 + 0] = (double)fi.x; xi[r][cb + 4 * m4 + 1] = (double)fi.y;
            xi[r][cb + 4 * m4 + 2] = (double)fi.z; xi[r][cb + 4 * m4 + 3] = (double)fi.w;
            xj[r][cb + 4 * m4 + 0] = (double)fj.x; xj[r][cb + 4 * m4 + 1] = (double)fj.y;
            xj[r][cb + 4 * m4 + 2] = (double)fj.z; xj[r][cb + 4 * m4 + 3] = (double)fj.w;
        }
    }
    __syncthreads();

    if (t < 128) {
        int row = t & 63;
        const double (*xs)[65] = (t < 64) ? xi : xj;
        double sum = 0.0, rr = 0.0;
#pragma unroll 8
        for (int c = 0; c < 64; ++c) { double v = xs[row][c]; sum += v; rr = fma(v, v, rr); }
        double m = sum / 64.0;
        double q = 0.0;
#pragma unroll 8
        for (int c = 0; c < 64; ++c) { double w = xs[row][c] - m; q = fma(w, w, q); }
        double sv = 1.0 / sqrt(q);
        if (t < 64) { mi[row] = m; ri_[row] = rr; si[row] = sv; }
        else        { mj[row] = m; rj_[row] = rr; sj[row] = sv; }
    }
    __syncthreads();

    int ty = t >> 4, tx = t & 15;
    double adot[4][4] = {};
    double amax[4][4] = {};
#pragma unroll 8
    for (int c = 0; c < 64; ++c) {
        double ai[4], aj[4];
#pragma unroll
        for (int p = 0; p < 4; ++p) ai[p] = xi[ty + 16 * p][c];
#pragma unroll
        for (int q = 0; q < 4; ++q) aj[q] = xj[tx + 16 * q][c];
#pragma unroll
        for (int p = 0; p < 4; ++p)
#pragma unroll
            for (int q = 0; q < 4; ++q) {
                double d = ai[p] - aj[q];
                amax[p][q] = fmax(amax[p][q], fabs(d));
                adot[p][q] = fma(ai[p], aj[q], adot[p][q]);
            }
    }

#pragma unroll
    for (int p = 0; p < 4; ++p) {
        int li = ty + 16 * p;
        int ii = i0 + li;
        double rri = ri_[li], mmi = mi[li], ssi = si[li];
#pragma unroll
        for (int q = 0; q < 4; ++q) {
            int lj = tx + 16 * q;
            int jj = j0 + lj;
            double dot = adot[p][q];
            double d2  = rri + rj_[lj] - 2.0 * dot;
            double e   = (ii == jj) ? 0.0 : sqrt(fmax(d2, 0.0));
            double cc  = (dot - 64.0 * mmi * mj[lj]) * ssi * sj[lj];
            cc = fmin(1.0, fmax(-1.0, cc));
            size_t idx = (size_t)b * S + (size_t)ii * N + jj;
            E[idx]  = e;
            Ch[idx] = amax[p][q];
            Cc[idx] = cc;
        }
    }
}

// ---------------------------------------------------------------------------
// K2: C = scale * A * B^T (fp64, MFMA). 64x64 tile, LDS double-buffered.
__global__ __launch_bounds__(256) void k_gemm_nt(const double* __restrict__ A,
                                                 const double* __restrict__ Bm,
                                                 double* __restrict__ Cm,
                                                 double scale) {
    int b = blockIdx.z;
    const double* Ab = A  + (size_t)b * S;
    const double* Bb = Bm + (size_t)b * S;
    double*       Cb = Cm + (size_t)b * S;
    int i0 = blockIdx.y * 64, j0 = blockIdx.x * 64;

    __shared__ double At[2][64][33];
    __shared__ double Bt[2][64][33];

    int t    = threadIdx.x;
    int lane = t & 63;
    int w    = t >> 6;
    int wr   = (w >> 1) * 32;
    int wc   = (w & 1) * 32;
    int fm   = lane & 15;
    int fk   = lane >> 4;

    int sr = t >> 2, sc0 = (t & 3) * 8;

    d4 acc00 = {0.0, 0.0, 0.0, 0.0};
    d4 acc01 = acc00, acc10 = acc00, acc11 = acc00;

    const double* ap = Ab + (size_t)(i0 + sr) * N + sc0;
    const double* bp = Bb + (size_t)(j0 + sr) * N + sc0;

    double pa[8], pb[8];
#pragma unroll
    for (int m = 0; m < 8; ++m) { pa[m] = ap[m]; pb[m] = bp[m]; }
#pragma unroll
    for (int m = 0; m < 8; ++m) { At[0][sr][sc0 + m] = pa[m]; Bt[0][sr][sc0 + m] = pb[m]; }
    __syncthreads();

    int cur = 0;
    for (int k0 = 0; k0 < N; k0 += 32) {
        bool has_next = (k0 + 32 < N);
        if (has_next) {
            ap += 32; bp += 32;
#pragma unroll
            for (int m = 0; m < 8; ++m) { pa[m] = ap[m]; pb[m] = bp[m]; }
        }
#pragma unroll
        for (int kq = 0; kq < 8; ++kq) {
            int kk = kq * 4 + fk;
            double a0 = At[cur][wr + fm][kk];
            double a1 = At[cur][wr + 16 + fm][kk];
            double b0 = Bt[cur][wc + fm][kk];
            double b1 = Bt[cur][wc + 16 + fm][kk];
            acc00 = __builtin_amdgcn_mfma_f64_16x16x4f64(a0, b0, acc00, 0, 0, 0);
            acc01 = __builtin_amdgcn_mfma_f64_16x16x4f64(a0, b1, acc01, 0, 0, 0);
            acc10 = __builtin_amdgcn_mfma_f64_16x16x4f64(a1, b0, acc10, 0, 0, 0);
            acc11 = __builtin_amdgcn_mfma_f64_16x16x4f64(a1, b1, acc11, 0, 0, 0);
        }
        if (has_next) {
            int nxt = cur ^ 1;
#pragma unroll
            for (int m = 0; m < 8; ++m) { At[nxt][sr][sc0 + m] = pa[m]; Bt[nxt][sr][sc0 + m] = pb[m]; }
            __syncthreads();
            cur = nxt;
        }
    }
    int r0 = i0 + wr + 4 * fk;
    int c0 = j0 + wc + fm;
#pragma unroll
    for (int r = 0; r < 4; ++r) {
        Cb[(size_t)(r0 + r)      * N + c0]      = acc00[r] * scale;
        Cb[(size_t)(r0 + r)      * N + c0 + 16] = acc01[r] * scale;
        Cb[(size_t)(r0 + 16 + r) * N + c0]      = acc10[r] * scale;
        Cb[(size_t)(r0 + 16 + r) * N + c0 + 16] = acc11[r] * scale;
    }
}

// ---------------------------------------------------------------------------
// K4: W = A * B (fp64, MFMA) + key32 epilogue.
__global__ __launch_bounds__(256) void k_gemm_nn(const double* __restrict__ A,
                                                 const double* __restrict__ Bm,
                                                 double* __restrict__ Wm,
                                                 unsigned int* __restrict__ kq_out) {
    int b = blockIdx.z;
    const double* Ab = A  + (size_t)b * S;
    const double* Bb = Bm + (size_t)b * S;
    double*       Wb = Wm + (size_t)b * S;
    unsigned int* kb = kq_out + (size_t)b * S;
    int i0 = blockIdx.y * 64, j0 = blockIdx.x * 64;

    __shared__ double At[2][64][33];
    __shared__ double Bt[2][32][65];

    int t    = threadIdx.x;
    int lane = t & 63;
    int w    = t >> 6;
    int wr   = (w >> 1) * 32;
    int wc   = (w & 1) * 32;
    int fm   = lane & 15;
    int fk   = lane >> 4;

    int sr = t >> 2, sc0 = (t & 3) * 8;   // A staging: 64 rows x 32 k
    int br = t >> 3, bc = (t & 7) * 8;    // B staging: 32 k x 64 cols

    d4 acc00 = {0.0, 0.0, 0.0, 0.0};
    d4 acc01 = acc00, acc10 = acc00, acc11 = acc00;

    const double* ap = Ab + (size_t)(i0 + sr) * N + sc0;
    const double* bp = Bb + (size_t)br * N + j0 + bc;

    double pa[8], pb[8];
#pragma unroll
    for (int m = 0; m < 8; ++m) { pa[m] = ap[m]; pb[m] = bp[m]; }
#pragma unroll
    for (int m = 0; m < 8; ++m) { At[0][sr][sc0 + m] = pa[m]; Bt[0][br][bc + m] = pb[m]; }
    __syncthreads();

    int cur = 0;
    for (int k0 = 0; k0 < N; k0 += 32) {
        bool has_next = (k0 + 32 < N);
        if (has_next) {
            ap += 32; bp += (size_t)32 * N;
#pragma unroll
            for (int m = 0; m < 8; ++m) { pa[m] = ap[m]; pb[m] = bp[m]; }
        }
#pragma unroll
        for (int kq = 0; kq < 8; ++kq) {
            int kk = kq * 4 + fk;
            double a0 = At[cur][wr + fm][kk];
            double a1 = At[cur][wr + 16 + fm][kk];
            double b0 = Bt[cur][kk][wc + fm];
            double b1 = Bt[cur][kk][wc + 16 + fm];
            acc00 = __builtin_amdgcn_mfma_f64_16x16x4f64(a0, b0, acc00, 0, 0, 0);
            acc01 = __builtin_amdgcn_mfma_f64_16x16x4f64(a0, b1, acc01, 0, 0, 0);
            acc10 = __builtin_amdgcn_mfma_f64_16x16x4f64(a1, b0, acc10, 0, 0, 0);
            acc11 = __builtin_amdgcn_mfma_f64_16x16x4f64(a1, b1, acc11, 0, 0, 0);
        }
        if (has_next) {
            int nxt = cur ^ 1;
#pragma unroll
            for (int m = 0; m < 8; ++m) { At[nxt][sr][sc0 + m] = pa[m]; Bt[nxt][br][bc + m] = pb[m]; }
            __syncthreads();
            cur = nxt;
        }
    }
    int r0 = i0 + wr + 4 * fk;
    int c0 = j0 + wc + fm;
#pragma unroll
    for (int r = 0; r < 4; ++r) {
        double w00 = acc00[r], w01 = acc01[r], w10 = acc10[r], w11 = acc11[r];
        size_t i00 = (size_t)(r0 + r)      * N + c0;
        size_t i01 = (size_t)(r0 + r)      * N + c0 + 16;
        size_t i10 = (size_t)(r0 + 16 + r) * N + c0;
        size_t i11 = (size_t)(r0 + 16 + r) * N + c0 + 16;
        Wb[i00] = w00; kb[i00] = (unsigned int)(d2key(w00) >> 32);
        Wb[i01] = w01; kb[i01] = (unsigned int)(d2key(w01) >> 32);
        Wb[i10] = w10; kb[i10] = (unsigned int)(d2key(w10) >> 32);
        Wb[i11] = w11; kb[i11] = (unsigned int)(d2key(w11) >> 32);
    }
}

// ---------------------------------------------------------------------------
// K3: fp64 row softmax. Wave per row, shuffle-only; 512 wgs.
__global__ __launch_bounds__(256) void k_softmax(double* __restrict__ L) {
    int row = (blockIdx.x << 2) + (threadIdx.x >> 6);
    int ln  = threadIdx.x & 63;
    double* p = L + (size_t)row * N;

    double v[16];
#pragma unroll
    for (int q = 0; q < 16; ++q) v[q] = p[ln + 64 * q];

    double mx = v[0];
#pragma unroll
    for (int q = 1; q < 16; ++q) mx = fmax(mx, v[q]);
#pragma unroll
    for (int off = 32; off >= 1; off >>= 1) mx = fmax(mx, __shfl_xor(mx, off));

    double s = 0.0;
#pragma unroll
    for (int q = 0; q < 16; ++q) { v[q] = exp(v[q] - mx); s += v[q]; }
#pragma unroll
    for (int off = 32; off >= 1; off >>= 1) s += __shfl_xor(s, off);

#pragma unroll
    for (int q = 0; q < 16; ++q) p[ln + 64 * q] = v[q] / s;
}

// ---------------------------------------------------------------------------
// Selection pipeline — separate kernels, no grid barriers, no spins.
// Scratch: g0[2][2048] (bits 31:21), g1[2][2048] (20:10), g2[2][1024] (9:0),
// cnt[2*16]. Zeroed by one hipMemsetAsync up front.

// hist level 0: bins = key >> 21.
__global__ __launch_bounds__(256) void k_hist0(const unsigned int* __restrict__ key32,
                                               unsigned int* __restrict__ g0) {
    __shared__ unsigned int lh[2048];
    int blk = blockIdx.x, t = threadIdx.x;
    int b = blk >> 7, lb = blk & 127;
    for (int i = t; i < 2048; i += 256) lh[i] = 0;
    __syncthreads();
    const uint4* k4 = (const uint4*)(key32 + (size_t)b * S + (size_t)lb * 8192);
#pragma unroll
    for (int it = 0; it < 8; ++it) {
        uint4 kv = k4[it * 256 + t];
        atomicAdd(&lh[kv.x >> 21], 1u);
        atomicAdd(&lh[kv.y >> 21], 1u);
        atomicAdd(&lh[kv.z >> 21], 1u);
        atomicAdd(&lh[kv.w >> 21], 1u);
    }
    __syncthreads();
    unsigned int* g = g0 + b * 2048;
    for (int i = t; i < 2048; i += 256)
        if (lh[i]) __hip_atomic_fetch_add(&g[i], lh[i], __ATOMIC_RELAXED,
                                          __HIP_MEMORY_SCOPE_AGENT);
}

// hist level 1: among (key>>21)==B0, bins = (key>>10)&0x7FF.
__global__ __launch_bounds__(256) void k_hist1(const unsigned int* __restrict__ key32,
                                               const unsigned int* __restrict__ g0,
                                               unsigned int* __restrict__ g1) {
    __shared__ unsigned int lh[2048];
    int blk = blockIdx.x, t = threadIdx.x;
    int b = blk >> 7, lb = blk & 127;
    unsigned int B0, kn;
    walk_level(g0 + b * 2048, 8, (unsigned int)KSEL, B0, kn);
    for (int i = t; i < 2048; i += 256) lh[i] = 0;
    __syncthreads();
    const uint4* k4 = (const uint4*)(key32 + (size_t)b * S + (size_t)lb * 8192);
#pragma unroll
    for (int it = 0; it < 8; ++it) {
        uint4 kv = k4[it * 256 + t];
        unsigned int ks[4] = {kv.x, kv.y, kv.z, kv.w};
#pragma unroll
        for (int c = 0; c < 4; ++c)
            if ((ks[c] >> 21) == B0) atomicAdd(&lh[(ks[c] >> 10) & 0x7FFu], 1u);
    }
    __syncthreads();
    unsigned int* g = g1 + b * 2048;
    for (int i = t; i < 2048; i += 256)
        if (lh[i]) __hip_atomic_fetch_add(&g[i], lh[i], __ATOMIC_RELAXED,
                                          __HIP_MEMORY_SCOPE_AGENT);
}

// hist level 2: among (key>>10)==(B0<<11|B1), bins = key & 0x3FF.
__global__ __launch_bounds__(256) void k_hist2(const unsigned int* __restrict__ key32,
                                               const unsigned int* __restrict__ g0,
                                               const unsigned int* __restrict__ g1,
                                               unsigned int* __restrict__ g2) {
    __shared__ unsigned int lh[1024];
    int blk = blockIdx.x, t = threadIdx.x;
    int b = blk >> 7, lb = blk & 127;
    unsigned int B0, B1, kn;
    walk_level(g0 + b * 2048, 8, (unsigned int)KSEL, B0, kn);
    walk_level(g1 + b * 2048, 8, kn, B1, kn);
    unsigned int P22 = (B0 << 11) | B1;
    for (int i = t; i < 1024; i += 256) lh[i] = 0;
    __syncthreads();
    const uint4* k4 = (const uint4*)(key32 + (size_t)b * S + (size_t)lb * 8192);
#pragma unroll
    for (int it = 0; it < 8; ++it) {
        uint4 kv = k4[it * 256 + t];
        unsigned int ks[4] = {kv.x, kv.y, kv.z, kv.w};
#pragma unroll
        for (int c = 0; c < 4; ++c)
            if ((ks[c] >> 10) == P22) atomicAdd(&lh[ks[c] & 0x3FFu], 1u);
    }
    __syncthreads();
    unsigned int* g = g2 + b * 1024;
    for (int i = t; i < 1024; i += 256)
        if (lh[i]) __hip_atomic_fetch_add(&g[i], lh[i], __ATOMIC_RELAXED,
                                          __HIP_MEMORY_SCOPE_AGENT);
}

// collect exact ties key == pref -> cand[(idx<<32)|low32], count in cnt[b*16].
__global__ __launch_bounds__(256) void k_collect(const unsigned int* __restrict__ key32,
                                                 const double* __restrict__ W,
                                                 const unsigned int* __restrict__ g0,
                                                 const unsigned int* __restrict__ g1,
                                                 const unsigned int* __restrict__ g2,
                                                 unsigned int* __restrict__ cnt,
                                                 unsigned long long* __restrict__ cand) {
    int blk = blockIdx.x, t = threadIdx.x;
    int b = blk >> 7, lb = blk & 127;
    int lane = t & 63;
    unsigned int B0, B1, B2, kn;
    walk_level(g0 + b * 2048, 8, (unsigned int)KSEL, B0, kn);
    walk_level(g1 + b * 2048, 8, kn, B1, kn);
    walk_level(g2 + b * 1024, 4, kn, B2, kn);
    unsigned int pref = (B0 << 21) | (B1 << 10) | B2;

    const uint4* k4 = (const uint4*)(key32 + (size_t)b * S + (size_t)lb * 8192);
    const double* Wb = W + (size_t)b * S;
    unsigned long long* cb = cand + (size_t)b * EQCAP;
    unsigned long long lmask = (1ULL << lane) - 1ULL;
#pragma unroll
    for (int it = 0; it < 8; ++it) {
        uint4 kv = k4[it * 256 + t];
        unsigned int ks[4] = {kv.x, kv.y, kv.z, kv.w};
#pragma unroll
        for (int c = 0; c < 4; ++c) {
            bool m = (ks[c] == pref);
            unsigned long long mb = __ballot(m);
            if (mb == 0ULL) continue;
            int ldr = __ffsll((long long)mb) - 1;
            unsigned int base = 0;
            if (lane == ldr)
                base = __hip_atomic_fetch_add(&cnt[b * 16], (unsigned int)__popcll(mb),
                                              __ATOMIC_RELAXED, __HIP_MEMORY_SCOPE_AGENT);
            base = __shfl(base, ldr, 64);
            if (m) {
                unsigned int pos = base + (unsigned int)__popcll(mb & lmask);
                if (pos < (unsigned int)EQCAP) {
                    int s = lb * 8192 + it * 1024 + t * 4 + c;
                    unsigned int low = (unsigned int)d2key(Wb[s]);
                    astore64(&cb[pos], (((unsigned long long)(unsigned int)s) << 32) | low);
                }
            }
        }
    }
}

// refine: one block per batch; 4 radix-8 passes on low32 + 3 on idx.
__global__ __launch_bounds__(256) void k_refine(const unsigned int* __restrict__ g0,
                                                const unsigned int* __restrict__ g1,
                                                const unsigned int* __restrict__ g2,
                                                const unsigned int* __restrict__ cnt,
                                                const unsigned long long* __restrict__ cand,
                                                unsigned int* __restrict__ pub2) {
    int b = blockIdx.x, t = threadIdx.x;
    unsigned int B0, B1, B2, kn;
    walk_level(g0 + b * 2048, 8, (unsigned int)KSEL, B0, kn);
    walk_level(g1 + b * 2048, 8, kn, B1, kn);
    walk_level(g2 + b * 1024, 4, kn, B2, kn);

    __shared__ int lh[256];
    __shared__ unsigned int sp, sk;
    const unsigned long long* cb = cand + (size_t)b * EQCAP;
    unsigned int c_ = cnt[b * 16];
    if (c_ > (unsigned int)EQCAP) c_ = EQCAP;

    unsigned int rpref = 0, rkneed = kn;
    for (int shift = 24; shift >= 0; shift -= 8) {
        lh[t] = 0;
        __syncthreads();
        for (unsigned int e = t; e < c_; e += 256) {
            unsigned int low = (unsigned int)cb[e];
            if ((((unsigned long long)(low ^ rpref)) >> (shift + 8)) == 0ULL)
                atomicAdd(&lh[(low >> shift) & 255u], 1);
        }
        __syncthreads();
        if (t == 0) {
            unsigned int cum = 0; int bucket = 0;
            for (int i = 255; i >= 0; --i) {
                unsigned int h = (unsigned int)lh[i];
                if (cum + h >= rkneed) { bucket = i; break; }
                cum += h;
            }
            sp = rpref | ((unsigned int)bucket << shift);
            sk = rkneed - cum;
        }
        __syncthreads();
        rpref = sp; rkneed = sk;
        __syncthreads();
    }
    unsigned int TL = rpref;
    unsigned int ipref = 0;
    for (int shift = 16; shift >= 0; shift -= 8) {
        lh[t] = 0;
        __syncthreads();
        for (unsigned int e = t; e < c_; e += 256) {
            unsigned long long pr = cb[e];
            if ((unsigned int)pr != TL) continue;
            unsigned int idx = (unsigned int)(pr >> 32);
            if ((((unsigned long long)(idx ^ ipref)) >> (shift + 8)) == 0ULL)
                atomicAdd(&lh[(idx >> shift) & 255u], 1);
        }
        __syncthreads();
        if (t == 0) {
            unsigned int cum = 0; int bucket = 0;
            for (int i = 255; i >= 0; --i) {
                unsigned int h = (unsigned int)lh[i];
                if (cum + h >= rkneed) { bucket = i; break; }
                cum += h;
            }
            sp = ipref | ((unsigned int)bucket << shift);
            sk = rkneed - cum;
        }
        __syncthreads();
        ipref = sp; rkneed = sk;
        __syncthreads();
    }
    if (t == 0) { pub2[b * 16] = TL; pub2[b * 16 + 1] = ipref; }
}

// final mask: pure streaming.
__global__ __launch_bounds__(256) void k_mask(const unsigned int* __restrict__ key32,
                                              const double* __restrict__ W,
                                              const unsigned int* __restrict__ g0,
                                              const unsigned int* __restrict__ g1,
                                              const unsigned int* __restrict__ g2,
                                              const unsigned int* __restrict__ pub2,
                                              float* __restrict__ out) {
    int blk = blockIdx.x, t = threadIdx.x;
    int b = blk >> 7, lb = blk & 127;
    unsigned int B0, B1, B2, kn;
    walk_level(g0 + b * 2048, 8, (unsigned int)KSEL, B0, kn);
    walk_level(g1 + b * 2048, 8, kn, B1, kn);
    walk_level(g2 + b * 1024, 4, kn, B2, kn);
    unsigned int pref = (B0 << 21) | (B1 << 10) | B2;
    unsigned int TL   = pub2[b * 16];
    unsigned int sCut = pub2[b * 16 + 1];

    const uint4* k4 = (const uint4*)(key32 + (size_t)b * S + (size_t)lb * 8192);
    const double* Wb = W + (size_t)b * S;
    float4* ob = (float4*)(out + (size_t)b * S + (size_t)lb * 8192);
#pragma unroll
    for (int it = 0; it < 8; ++it) {
        uint4 kv = k4[it * 256 + t];
        unsigned int ks[4] = {kv.x, kv.y, kv.z, kv.w};
        float ov[4];
#pragma unroll
        for (int c = 0; c < 4; ++c) {
            float v = 0.0f;
            if (ks[c] > pref) {
                v = 1.0f;
            } else if (ks[c] == pref) {
                int s = lb * 8192 + it * 1024 + t * 4 + c;
                unsigned int low = (unsigned int)d2key(Wb[s]);
                v = (low > TL || (low == TL && (unsigned int)s >= sCut)) ? 1.0f : 0.0f;
            }
            ov[c] = v;
        }
        ob[it * 256 + t] = make_float4(ov[0], ov[1], ov[2], ov[3]);
    }
}

// ---------------------------------------------------------------------------
extern "C" void kernel_launch(void* const* d_in, const int* in_sizes, int n_in,
                              void* d_out, int out_size, void* d_ws, size_t ws_size,
                              hipStream_t stream) {
    const float* x = (const float*)d_in[0];
    float* out = (float*)d_out;

    char* ws = (char*)d_ws;
    size_t off = 0;
    auto alloc = [&](size_t bytes) -> void* {
        void* p = ws + off;
        off += (bytes + 255) & ~(size_t)255;
        return p;
    };

    double* E     = (double*)alloc((size_t)BB * S * sizeof(double));       // 16 MB
    double* Ch    = (double*)alloc((size_t)BB * S * sizeof(double));       // 16 MB
    double* Cc    = (double*)alloc((size_t)BB * S * sizeof(double));       // 16 MB
    double* L     = (double*)alloc((size_t)BB * S * sizeof(double));       // 16 MB
    unsigned int* key32 = (unsigned int*)alloc((size_t)BB * S * sizeof(unsigned int)); // 8 MB
    double* W     = E;  // E dead after gemm_nt -> reuse for weighted

    // selection scratch (one contiguous memset region)
    unsigned int* sel = (unsigned int*)alloc(10272 * sizeof(unsigned int));
    unsigned int* g0   = sel;           // [2][2048]
    unsigned int* g1   = sel + 4096;    // [2][2048]
    unsigned int* g2   = sel + 8192;    // [2][1024]
    unsigned int* cnt  = sel + 10240;   // [2*16]
    unsigned int* pub2 = (unsigned int*)alloc(128);   // written by refine
    unsigned long long* cand =
        (unsigned long long*)alloc((size_t)BB * EQCAP * sizeof(unsigned long long)); // 2 MB

    // 0) zero selection scratch
    hipMemsetAsync(sel, 0, 10272 * sizeof(unsigned int), stream);

    // 1) pairwise adjacencies (fused per-row stats)
    k_pairwise<<<dim3(N / 64, N / 64, BB), 256, 0, stream>>>(x, E, Ch, Cc);

    // 2) logits = (E @ Ch^T) * 1/8
    k_gemm_nt<<<dim3(N / 64, N / 64, BB), 256, 0, stream>>>(E, Ch, L, 0.125);

    // 3) softmax rows
    k_softmax<<<512, 256, 0, stream>>>(L);

    // 4) weighted = attn @ Cc + key32 epilogue
    k_gemm_nn<<<dim3(N / 64, N / 64, BB), 256, 0, stream>>>(L, Cc, W, key32);

    // 5) selection: 3-level radix (11/11/10 bits) + collect + refine + mask
    k_hist0<<<256, 256, 0, stream>>>(key32, g0);
    k_hist1<<<256, 256, 0, stream>>>(key32, g0, g1);
    k_hist2<<<256, 256, 0, stream>>>(key32, g0, g1, g2);
    k_collect<<<256, 256, 0, stream>>>(key32, W, g0, g1, g2, cnt, cand);
    k_refine<<<BB, 256, 0, stream>>>(g0, g1, g2, cnt, cand, pub2);
    k_mask<<<256, 256, 0, stream>>>(key32, W, g0, g1, g2, pub2, out);
}

// Round 13
// 398.635 us; speedup vs baseline: 1.1537x; 1.1537x over previous
//
#include <hip/hip_runtime.h>
#include <hip/hip_bf16.h>

// Problem constants (from setup_inputs: x = [2, 1024, 64] fp32)
constexpr int BB = 2;
constexpr int N  = 1024;
constexpr int C  = 64;
constexpr int S  = N * N;          // 1048576 = 2^20
constexpr int KSEL = S / 6;        // 174762 entries set to 1 per batch
constexpr int EQCAP = S;           // tie capacity per batch == batch size (unconditional)
constexpr int NSELBLK = 256;

typedef double d4 __attribute__((ext_vector_type(4)));

// Order-preserving uint64 mapping of fp64 (monotone: a<b <=> key(a)<key(b))
__device__ __forceinline__ unsigned long long d2key(double d) {
    unsigned long long u = (unsigned long long)__double_as_longlong(d);
    return (u & 0x8000000000000000ULL) ? ~u : (u | 0x8000000000000000ULL);
}

__device__ __forceinline__ unsigned int aload(const unsigned int* p) {
    return __hip_atomic_load(p, __ATOMIC_RELAXED, __HIP_MEMORY_SCOPE_AGENT);
}
__device__ __forceinline__ void astore(unsigned int* p, unsigned int v) {
    (void)__hip_atomic_exchange(p, v, __ATOMIC_RELAXED, __HIP_MEMORY_SCOPE_AGENT);
}
__device__ __forceinline__ unsigned long long aload64(const unsigned long long* p) {
    return __hip_atomic_load(p, __ATOMIC_RELAXED, __HIP_MEMORY_SCOPE_AGENT);
}
__device__ __forceinline__ void astore64(unsigned long long* p, unsigned long long v) {
    (void)__hip_atomic_exchange(p, v, __ATOMIC_RELAXED, __HIP_MEMORY_SCOPE_AGENT);
}

// Two-level scan over an nbins histogram (cs = nbins/256 per thread): largest
// bucket such that the count of entries in buckets >= it reaches kneed.
// Reads via agent-scope atomic loads (hist may be written by other blocks
// within this kernel, only a spin barrier in between — no kernel-boundary
// acquire to rely on).
__device__ __forceinline__ void walk_level(const unsigned int* __restrict__ g, int cs,
                                           unsigned int kneed_in,
                                           unsigned int& bucket, unsigned int& kneed_out) {
    __shared__ unsigned int chunks[256];
    __shared__ unsigned int res[2];
    __shared__ unsigned int row[8];
    int t = threadIdx.x;
    unsigned int s = 0;
    for (int i = 0; i < cs; ++i) s += aload(&g[t * cs + i]);
    chunks[t] = s;
    __syncthreads();
    if (t == 0) {
        unsigned int cum = 0; int Cc_ = 0;
        for (int ch = 255; ch >= 0; --ch) {
            if (cum + chunks[ch] >= kneed_in) { Cc_ = ch; break; }
            cum += chunks[ch];
        }
        unsigned int bkt = 0, kn = 1;
        for (int i = cs - 1; i >= 0; --i) {
            unsigned int h = aload(&g[Cc_ * cs + i]);
            if (cum + h >= kneed_in) { bkt = (unsigned int)(Cc_ * cs + i); kn = kneed_in - cum; break; }
            cum += h;
        }
        res[0] = bkt; res[1] = kn;
    }
    __syncthreads();
    bucket = res[0]; kneed_out = res[1];
    __syncthreads();
    (void)row;
}

// ---------------------------------------------------------------------------
// K1: pairwise adjacencies with fused per-row stats. 64x64 tile (512 wgs).
__global__ __launch_bounds__(256) void k_pairwise(const float* __restrict__ x,
                                                  double* __restrict__ E,
                                                  double* __restrict__ Ch,
                                                  double* __restrict__ Cc) {
    int b  = blockIdx.z;
    int i0 = blockIdx.y * 64;
    int j0 = blockIdx.x * 64;
    __shared__ double xi[64][65];
    __shared__ double xj[64][65];
    __shared__ double mi[64], ri_[64], si[64];
    __shared__ double mj[64], rj_[64], sj[64];

    int t  = threadIdx.x;
    int r  = t >> 2;
    int cb = (t & 3) * 16;
    const float* xb = x + (size_t)b * N * C;
    {
        const float4* pi = (const float4*)(xb + (size_t)(i0 + r) * C + cb);
        const float4* pj = (const float4*)(xb + (size_t)(j0 + r) * C + cb);
#pragma unroll
        for (int m4 = 0; m4 < 4; ++m4) {
            float4 fi = pi[m4], fj = pj[m4];
            xi[r][cb + 4 * m4 + 0] = (double)fi.x; xi[r][cb + 4 * m4 + 1] = (double)fi.y;
            xi[r][cb + 4 * m4 + 2] = (double)fi.z; xi[r][cb + 4 * m4 + 3] = (double)fi.w;
            xj[r][cb + 4 * m4 + 0] = (double)fj.x; xj[r][cb + 4 * m4 + 1] = (double)fj.y;
            xj[r][cb + 4 * m4 + 2] = (double)fj.z; xj[r][cb + 4 * m4 + 3] = (double)fj.w;
        }
    }
    __syncthreads();

    if (t < 128) {
        int row = t & 63;
        const double (*xs)[65] = (t < 64) ? xi : xj;
        double sum = 0.0, rr = 0.0;
#pragma unroll 8
        for (int c = 0; c < 64; ++c) { double v = xs[row][c]; sum += v; rr = fma(v, v, rr); }
        double m = sum / 64.0;
        double q = 0.0;
#pragma unroll 8
        for (int c = 0; c < 64; ++c) { double w = xs[row][c] - m; q = fma(w, w, q); }
        double sv = 1.0 / sqrt(q);
        if (t < 64) { mi[row] = m; ri_[row] = rr; si[row] = sv; }
        else        { mj[row] = m; rj_[row] = rr; sj[row] = sv; }
    }
    __syncthreads();

    int ty = t >> 4, tx = t & 15;
    double adot[4][4] = {};
    double amax[4][4] = {};
#pragma unroll 8
    for (int c = 0; c < 64; ++c) {
        double ai[4], aj[4];
#pragma unroll
        for (int p = 0; p < 4; ++p) ai[p] = xi[ty + 16 * p][c];
#pragma unroll
        for (int q = 0; q < 4; ++q) aj[q] = xj[tx + 16 * q][c];
#pragma unroll
        for (int p = 0; p < 4; ++p)
#pragma unroll
            for (int q = 0; q < 4; ++q) {
                double d = ai[p] - aj[q];
                amax[p][q] = fmax(amax[p][q], fabs(d));
                adot[p][q] = fma(ai[p], aj[q], adot[p][q]);
            }
    }

#pragma unroll
    for (int p = 0; p < 4; ++p) {
        int li = ty + 16 * p;
        int ii = i0 + li;
        double rri = ri_[li], mmi = mi[li], ssi = si[li];
#pragma unroll
        for (int q = 0; q < 4; ++q) {
            int lj = tx + 16 * q;
            int jj = j0 + lj;
            double dot = adot[p][q];
            double d2  = rri + rj_[lj] - 2.0 * dot;
            double e   = (ii == jj) ? 0.0 : sqrt(fmax(d2, 0.0));
            double cc  = (dot - 64.0 * mmi * mj[lj]) * ssi * sj[lj];
            cc = fmin(1.0, fmax(-1.0, cc));
            size_t idx = (size_t)b * S + (size_t)ii * N + jj;
            E[idx]  = e;
            Ch[idx] = amax[p][q];
            Cc[idx] = cc;
        }
    }
}

// ---------------------------------------------------------------------------
// K2: C = scale * A * B^T (fp64, MFMA). 64x64 tile, LDS double-buffered.
__global__ __launch_bounds__(256) void k_gemm_nt(const double* __restrict__ A,
                                                 const double* __restrict__ Bm,
                                                 double* __restrict__ Cm,
                                                 double scale) {
    int b = blockIdx.z;
    const double* Ab = A  + (size_t)b * S;
    const double* Bb = Bm + (size_t)b * S;
    double*       Cb = Cm + (size_t)b * S;
    int i0 = blockIdx.y * 64, j0 = blockIdx.x * 64;

    __shared__ double At[2][64][33];
    __shared__ double Bt[2][64][33];

    int t    = threadIdx.x;
    int lane = t & 63;
    int w    = t >> 6;
    int wr   = (w >> 1) * 32;
    int wc   = (w & 1) * 32;
    int fm   = lane & 15;
    int fk   = lane >> 4;

    int sr = t >> 2, sc0 = (t & 3) * 8;

    d4 acc00 = {0.0, 0.0, 0.0, 0.0};
    d4 acc01 = acc00, acc10 = acc00, acc11 = acc00;

    const double* ap = Ab + (size_t)(i0 + sr) * N + sc0;
    const double* bp = Bb + (size_t)(j0 + sr) * N + sc0;

    double pa[8], pb[8];
#pragma unroll
    for (int m = 0; m < 8; ++m) { pa[m] = ap[m]; pb[m] = bp[m]; }
#pragma unroll
    for (int m = 0; m < 8; ++m) { At[0][sr][sc0 + m] = pa[m]; Bt[0][sr][sc0 + m] = pb[m]; }
    __syncthreads();

    int cur = 0;
    for (int k0 = 0; k0 < N; k0 += 32) {
        bool has_next = (k0 + 32 < N);
        if (has_next) {
            ap += 32; bp += 32;
#pragma unroll
            for (int m = 0; m < 8; ++m) { pa[m] = ap[m]; pb[m] = bp[m]; }
        }
#pragma unroll
        for (int kq = 0; kq < 8; ++kq) {
            int kk = kq * 4 + fk;
            double a0 = At[cur][wr + fm][kk];
            double a1 = At[cur][wr + 16 + fm][kk];
            double b0 = Bt[cur][wc + fm][kk];
            double b1 = Bt[cur][wc + 16 + fm][kk];
            acc00 = __builtin_amdgcn_mfma_f64_16x16x4f64(a0, b0, acc00, 0, 0, 0);
            acc01 = __builtin_amdgcn_mfma_f64_16x16x4f64(a0, b1, acc01, 0, 0, 0);
            acc10 = __builtin_amdgcn_mfma_f64_16x16x4f64(a1, b0, acc10, 0, 0, 0);
            acc11 = __builtin_amdgcn_mfma_f64_16x16x4f64(a1, b1, acc11, 0, 0, 0);
        }
        if (has_next) {
            int nxt = cur ^ 1;
#pragma unroll
            for (int m = 0; m < 8; ++m) { At[nxt][sr][sc0 + m] = pa[m]; Bt[nxt][sr][sc0 + m] = pb[m]; }
            __syncthreads();
            cur = nxt;
        }
    }
    int r0 = i0 + wr + 4 * fk;
    int c0 = j0 + wc + fm;
#pragma unroll
    for (int r = 0; r < 4; ++r) {
        Cb[(size_t)(r0 + r)      * N + c0]      = acc00[r] * scale;
        Cb[(size_t)(r0 + r)      * N + c0 + 16] = acc01[r] * scale;
        Cb[(size_t)(r0 + 16 + r) * N + c0]      = acc10[r] * scale;
        Cb[(size_t)(r0 + 16 + r) * N + c0 + 16] = acc11[r] * scale;
    }
}

// ---------------------------------------------------------------------------
// K4: W = A * B (fp64, MFMA) + key32 epilogue + FUSED hist0 (bins key>>21,
// 2048 bins, 8 KB extra LDS). Removes one full selection pass.
__global__ __launch_bounds__(256) void k_gemm_nn(const double* __restrict__ A,
                                                 const double* __restrict__ Bm,
                                                 double* __restrict__ Wm,
                                                 unsigned int* __restrict__ kq_out,
                                                 unsigned int* __restrict__ g0) {
    int b = blockIdx.z;
    const double* Ab = A  + (size_t)b * S;
    const double* Bb = Bm + (size_t)b * S;
    double*       Wb = Wm + (size_t)b * S;
    unsigned int* kb = kq_out + (size_t)b * S;
    int i0 = blockIdx.y * 64, j0 = blockIdx.x * 64;

    __shared__ double At[2][64][33];
    __shared__ double Bt[2][32][65];
    __shared__ unsigned int h0[2048];

    int t    = threadIdx.x;
    int lane = t & 63;
    int w    = t >> 6;
    int wr   = (w >> 1) * 32;
    int wc   = (w & 1) * 32;
    int fm   = lane & 15;
    int fk   = lane >> 4;

    int sr = t >> 2, sc0 = (t & 3) * 8;   // A staging: 64 rows x 32 k
    int br = t >> 3, bc = (t & 7) * 8;    // B staging: 32 k x 64 cols

    for (int i = t; i < 2048; i += 256) h0[i] = 0u;

    d4 acc00 = {0.0, 0.0, 0.0, 0.0};
    d4 acc01 = acc00, acc10 = acc00, acc11 = acc00;

    const double* ap = Ab + (size_t)(i0 + sr) * N + sc0;
    const double* bp = Bb + (size_t)br * N + j0 + bc;

    double pa[8], pb[8];
#pragma unroll
    for (int m = 0; m < 8; ++m) { pa[m] = ap[m]; pb[m] = bp[m]; }
#pragma unroll
    for (int m = 0; m < 8; ++m) { At[0][sr][sc0 + m] = pa[m]; Bt[0][br][bc + m] = pb[m]; }
    __syncthreads();

    int cur = 0;
    for (int k0 = 0; k0 < N; k0 += 32) {
        bool has_next = (k0 + 32 < N);
        if (has_next) {
            ap += 32; bp += (size_t)32 * N;
#pragma unroll
            for (int m = 0; m < 8; ++m) { pa[m] = ap[m]; pb[m] = bp[m]; }
        }
#pragma unroll
        for (int kq = 0; kq < 8; ++kq) {
            int kk = kq * 4 + fk;
            double a0 = At[cur][wr + fm][kk];
            double a1 = At[cur][wr + 16 + fm][kk];
            double b0 = Bt[cur][kk][wc + fm];
            double b1 = Bt[cur][kk][wc + 16 + fm];
            acc00 = __builtin_amdgcn_mfma_f64_16x16x4f64(a0, b0, acc00, 0, 0, 0);
            acc01 = __builtin_amdgcn_mfma_f64_16x16x4f64(a0, b1, acc01, 0, 0, 0);
            acc10 = __builtin_amdgcn_mfma_f64_16x16x4f64(a1, b0, acc10, 0, 0, 0);
            acc11 = __builtin_amdgcn_mfma_f64_16x16x4f64(a1, b1, acc11, 0, 0, 0);
        }
        if (has_next) {
            int nxt = cur ^ 1;
#pragma unroll
            for (int m = 0; m < 8; ++m) { At[nxt][sr][sc0 + m] = pa[m]; Bt[nxt][br][bc + m] = pb[m]; }
            __syncthreads();
            cur = nxt;
        }
    }
    int r0 = i0 + wr + 4 * fk;
    int c0 = j0 + wc + fm;
#pragma unroll
    for (int r = 0; r < 4; ++r) {
        double w00 = acc00[r], w01 = acc01[r], w10 = acc10[r], w11 = acc11[r];
        size_t i00 = (size_t)(r0 + r)      * N + c0;
        size_t i01 = (size_t)(r0 + r)      * N + c0 + 16;
        size_t i10 = (size_t)(r0 + 16 + r) * N + c0;
        size_t i11 = (size_t)(r0 + 16 + r) * N + c0 + 16;
        unsigned int k00 = (unsigned int)(d2key(w00) >> 32);
        unsigned int k01 = (unsigned int)(d2key(w01) >> 32);
        unsigned int k10 = (unsigned int)(d2key(w10) >> 32);
        unsigned int k11 = (unsigned int)(d2key(w11) >> 32);
        Wb[i00] = w00; kb[i00] = k00;
        Wb[i01] = w01; kb[i01] = k01;
        Wb[i10] = w10; kb[i10] = k10;
        Wb[i11] = w11; kb[i11] = k11;
        atomicAdd(&h0[k00 >> 21], 1u);
        atomicAdd(&h0[k01 >> 21], 1u);
        atomicAdd(&h0[k10 >> 21], 1u);
        atomicAdd(&h0[k11 >> 21], 1u);
    }
    __syncthreads();
    unsigned int* g = g0 + b * 2048;
    for (int i = t; i < 2048; i += 256)
        if (h0[i]) __hip_atomic_fetch_add(&g[i], h0[i], __ATOMIC_RELAXED,
                                          __HIP_MEMORY_SCOPE_AGENT);
}

// ---------------------------------------------------------------------------
// K3: fp64 row softmax. Wave per row, shuffle-only; 512 wgs.
__global__ __launch_bounds__(256) void k_softmax(double* __restrict__ L) {
    int row = (blockIdx.x << 2) + (threadIdx.x >> 6);
    int ln  = threadIdx.x & 63;
    double* p = L + (size_t)row * N;

    double v[16];
#pragma unroll
    for (int q = 0; q < 16; ++q) v[q] = p[ln + 64 * q];

    double mx = v[0];
#pragma unroll
    for (int q = 1; q < 16; ++q) mx = fmax(mx, v[q]);
#pragma unroll
    for (int off = 32; off >= 1; off >>= 1) mx = fmax(mx, __shfl_xor(mx, off));

    double s = 0.0;
#pragma unroll
    for (int q = 0; q < 16; ++q) { v[q] = exp(v[q] - mx); s += v[q]; }
#pragma unroll
    for (int off = 32; off >= 1; off >>= 1) s += __shfl_xor(s, off);

#pragma unroll
    for (int q = 0; q < 16; ++q) p[ln + 64 * q] = v[q] / s;
}

// ---------------------------------------------------------------------------
// K5: fused selection with TWO full passes and TWO grid barriers.
// Phase 1: walk g0 -> B0; hist middle 11 bits -> g1.  [pass 1]
// Phase 2: walk g1 -> 22-bit prefix; write mask for non-tie elements, collect
//          ties as packed (key10<<52 | low32<<20 | idx).  [pass 2]
// Phase 3: leader radix-selects packed cutoff; then EVERY block fixes up its
//          OWN tile's tie elements (owner-only writes -> no cross-XCD dirty-
//          line merge hazard on out).
__device__ __forceinline__ void gridbar(unsigned int* bar, unsigned int* phase) {
    asm volatile("s_waitcnt vmcnt(0)" ::: "memory");
    __syncthreads();
    if (threadIdx.x == 0) {
        unsigned int ph = ++(*phase);
        int g = (int)(blockIdx.x >> 4);
        unsigned int a1 = __hip_atomic_fetch_add(&bar[32 + g * 16], 1u,
                              __ATOMIC_RELAXED, __HIP_MEMORY_SCOPE_AGENT) + 1u;
        if (a1 == ph * 16u) {
            unsigned int a2 = __hip_atomic_fetch_add(&bar[0], 1u,
                                  __ATOMIC_RELAXED, __HIP_MEMORY_SCOPE_AGENT) + 1u;
            if (a2 == ph * 16u) astore(&bar[16], ph);
        }
        while (aload(&bar[16]) < ph) __builtin_amdgcn_s_sleep(4);
        asm volatile("" ::: "memory");
    }
    __syncthreads();
}

__global__ __launch_bounds__(256) void k_select(const unsigned int* __restrict__ key32,
                                                const double* __restrict__ W,
                                                const unsigned int* __restrict__ g0,
                                                unsigned int* __restrict__ g1,
                                                unsigned int* __restrict__ cnt,
                                                unsigned long long* __restrict__ cand,
                                                unsigned long long* __restrict__ pub,
                                                unsigned int* __restrict__ bar,
                                                float* __restrict__ out) {
    int blk = blockIdx.x, t = threadIdx.x;
    int b = blk >> 7, lb = blk & 127;
    int lane = t & 63;
    unsigned int phase = 0;

    __shared__ unsigned int lh[2048];
    __shared__ unsigned long long s_p64;
    __shared__ unsigned int s_kk;

    const uint4* k4 = (const uint4*)(key32 + (size_t)b * S + (size_t)lb * 8192);

    // ---- phase 1: hist over middle 11 bits among (key>>21)==B0 ----
    unsigned int B0, kn1;
    walk_level(g0 + b * 2048, 8, (unsigned int)KSEL, B0, kn1);
    for (int i = t; i < 2048; i += 256) lh[i] = 0;
    __syncthreads();
#pragma unroll
    for (int it = 0; it < 8; ++it) {
        uint4 kv = k4[it * 256 + t];
        unsigned int ks[4] = {kv.x, kv.y, kv.z, kv.w};
#pragma unroll
        for (int c = 0; c < 4; ++c)
            if ((ks[c] >> 21) == B0) atomicAdd(&lh[(ks[c] >> 10) & 0x7FFu], 1u);
    }
    __syncthreads();
    for (int i = t; i < 2048; i += 256)
        if (lh[i]) __hip_atomic_fetch_add(&g1[b * 2048 + i], lh[i], __ATOMIC_RELAXED,
                                          __HIP_MEMORY_SCOPE_AGENT);
    gridbar(bar, &phase);

    // ---- phase 2: final mask for non-ties + tie collection ----
    unsigned int B1, kn2;
    walk_level(g1 + b * 2048, 8, kn1, B1, kn2);
    unsigned int pref22 = (B0 << 11) | B1;

    unsigned long long lmask = (1ULL << lane) - 1ULL;
    unsigned long long* cb = cand + (size_t)b * EQCAP;
    const double* Wb = W + (size_t)b * S;
    float4* ob = (float4*)(out + (size_t)b * S + (size_t)lb * 8192);
#pragma unroll
    for (int it = 0; it < 8; ++it) {
        uint4 kv = k4[it * 256 + t];
        unsigned int ks[4] = {kv.x, kv.y, kv.z, kv.w};
        float ov[4];
#pragma unroll
        for (int c = 0; c < 4; ++c) {
            unsigned int k = ks[c];
            unsigned int t22 = k >> 10;
            bool m = (t22 == pref22);
            unsigned long long mb = __ballot(m);
            ov[c] = (t22 > pref22) ? 1.0f : 0.0f;   // ties: placeholder, fixed phase 3
            if (mb != 0ULL) {
                int ldr = __ffsll((long long)mb) - 1;
                unsigned int base = 0;
                if (lane == ldr)
                    base = __hip_atomic_fetch_add(&cnt[b * 16], (unsigned int)__popcll(mb),
                                                  __ATOMIC_RELAXED, __HIP_MEMORY_SCOPE_AGENT);
                base = __shfl(base, ldr, 64);
                if (m) {
                    unsigned int pos = base + (unsigned int)__popcll(mb & lmask);
                    if (pos < (unsigned int)EQCAP) {
                        int s = lb * 8192 + it * 1024 + t * 4 + c;
                        unsigned long long full = d2key(Wb[s]);
                        unsigned long long packed =
                            (((unsigned long long)(k & 0x3FFu)) << 52) |
                            ((full & 0xFFFFFFFFULL) << 20) |
                            (unsigned long long)(unsigned int)s;
                        astore64(&cb[pos], packed);
                    }
                }
            }
        }
        ob[it * 256 + t] = make_float4(ov[0], ov[1], ov[2], ov[3]);
    }
    gridbar(bar, &phase);

    // ---- phase 3a: leader per batch radix-selects the packed cutoff ----
    if (lb == 0) {
        unsigned int c_ = aload(&cnt[b * 16]);
        if (c_ > (unsigned int)EQCAP) c_ = EQCAP;
        unsigned long long rpref = 0ULL;
        unsigned int rk = kn2;
#pragma unroll 1
        for (int pass = 0; pass < 8; ++pass) {
            int shift = 56 - 8 * pass;
            lh[t] = 0;
            __syncthreads();
            for (unsigned int e = t; e < c_; e += 256) {
                unsigned long long p = aload64(&cb[e]);
                bool match = (pass == 0) || ((p >> (shift + 8)) == (rpref >> (shift + 8)));
                if (match) atomicAdd(&lh[(unsigned int)((p >> shift) & 255ULL)], 1u);
            }
            __syncthreads();
            if (t == 0) {
                unsigned int cum = 0; int bucket = 0;
                for (int i = 255; i >= 0; --i) {
                    unsigned int h = lh[i];
                    if (cum + h >= rk) { bucket = i; break; }
                    cum += h;
                }
                s_p64 = rpref | (((unsigned long long)bucket) << shift);
                s_kk  = rk - cum;
            }
            __syncthreads();
            rpref = s_p64; rk = s_kk;
            __syncthreads();
        }
        if (t == 0) astore64(&pub[b * 8], (1ULL << 63) | rpref);
    }

    // ---- phase 3b: every block fixes up its OWN tile's ties ----
    if (t == 0) {
        unsigned long long v;
        while (((v = aload64(&pub[b * 8])) >> 63) == 0ULL) __builtin_amdgcn_s_sleep(4);
        s_p64 = v;
    }
    __syncthreads();
    unsigned long long Ccut = s_p64 & 0x7FFFFFFFFFFFFFFFULL;

    float* outb = out + (size_t)b * S;
#pragma unroll
    for (int it = 0; it < 8; ++it) {
        uint4 kv = k4[it * 256 + t];
        unsigned int ks[4] = {kv.x, kv.y, kv.z, kv.w};
#pragma unroll
        for (int c = 0; c < 4; ++c) {
            unsigned int k = ks[c];
            if ((k >> 10) == pref22) {
                int s = lb * 8192 + it * 1024 + t * 4 + c;
                unsigned long long full = d2key(Wb[s]);
                unsigned long long packed =
                    (((unsigned long long)(k & 0x3FFu)) << 52) |
                    ((full & 0xFFFFFFFFULL) << 20) |
                    (unsigned long long)(unsigned int)s;
                outb[s] = (packed >= Ccut) ? 1.0f : 0.0f;   // same thread wrote
            }                                               // the placeholder
        }
    }
}

// ---------------------------------------------------------------------------
extern "C" void kernel_launch(void* const* d_in, const int* in_sizes, int n_in,
                              void* d_out, int out_size, void* d_ws, size_t ws_size,
                              hipStream_t stream) {
    const float* x = (const float*)d_in[0];
    float* out = (float*)d_out;

    char* ws = (char*)d_ws;
    size_t off = 0;
    auto alloc = [&](size_t bytes) -> void* {
        void* p = ws + off;
        off += (bytes + 255) & ~(size_t)255;
        return p;
    };

    double* E     = (double*)alloc((size_t)BB * S * sizeof(double));       // 16 MB
    double* Ch    = (double*)alloc((size_t)BB * S * sizeof(double));       // 16 MB
    double* Cc    = (double*)alloc((size_t)BB * S * sizeof(double));       // 16 MB
    double* L     = (double*)alloc((size_t)BB * S * sizeof(double));       // 16 MB
    unsigned int* key32 = (unsigned int*)alloc((size_t)BB * S * sizeof(unsigned int)); // 8 MB
    double* W     = E;  // E dead after gemm_nt -> reuse for weighted

    // selection scratch (one contiguous memset region): g0, g1, cnt, pub, bar
    unsigned int* selz = (unsigned int*)alloc((4096 + 4096 + 32 + 32 + 512) * sizeof(unsigned int));
    unsigned int* g0   = selz;                 // [2][2048]
    unsigned int* g1   = selz + 4096;          // [2][2048]
    unsigned int* cnt  = selz + 8192;          // [2*16]
    unsigned long long* pub = (unsigned long long*)(selz + 8224);   // [2*8] u64
    unsigned int* bar  = selz + 8256;          // barrier tree (512 u32)
    unsigned long long* cand =
        (unsigned long long*)alloc((size_t)BB * EQCAP * sizeof(unsigned long long)); // 16 MB

    // 0) zero selection scratch (g0/g1/cnt/pub/bar — ws is poisoned 0xAA)
    hipMemsetAsync(selz, 0, (4096 + 4096 + 32 + 32 + 512) * sizeof(unsigned int), stream);

    // 1) pairwise adjacencies (fused per-row stats)
    k_pairwise<<<dim3(N / 64, N / 64, BB), 256, 0, stream>>>(x, E, Ch, Cc);

    // 2) logits = (E @ Ch^T) * 1/8
    k_gemm_nt<<<dim3(N / 64, N / 64, BB), 256, 0, stream>>>(E, Ch, L, 0.125);

    // 3) softmax rows
    k_softmax<<<512, 256, 0, stream>>>(L);

    // 4) weighted = attn @ Cc + key32 epilogue + fused hist0
    k_gemm_nn<<<dim3(N / 64, N / 64, BB), 256, 0, stream>>>(L, Cc, W, key32, g0);

    // 5) fused selection (2 full passes, 2 grid barriers, owner-block fixup)
    k_select<<<NSELBLK, 256, 0, stream>>>(key32, W, g0, g1, cnt, cand, pub, bar, out);
}

// Round 14
// 395.922 us; speedup vs baseline: 1.1616x; 1.0069x over previous
//
#include <hip/hip_runtime.h>
#include <hip/hip_bf16.h>

// Problem constants (from setup_inputs: x = [2, 1024, 64] fp32)
constexpr int BB = 2;
constexpr int N  = 1024;
constexpr int C  = 64;
constexpr int S  = N * N;          // 1048576 = 2^20
constexpr int KSEL = S / 6;        // 174762 entries set to 1 per batch
constexpr int EQCAP = S;           // tie capacity per batch == batch size
constexpr int NSELBLK = 256;

typedef double d4 __attribute__((ext_vector_type(4)));

// Order-preserving uint64 mapping of fp64 (monotone: a<b <=> key(a)<key(b))
__device__ __forceinline__ unsigned long long d2key(double d) {
    unsigned long long u = (unsigned long long)__double_as_longlong(d);
    return (u & 0x8000000000000000ULL) ? ~u : (u | 0x8000000000000000ULL);
}

__device__ __forceinline__ unsigned int aload(const unsigned int* p) {
    return __hip_atomic_load(p, __ATOMIC_RELAXED, __HIP_MEMORY_SCOPE_AGENT);
}
__device__ __forceinline__ void astore(unsigned int* p, unsigned int v) {
    (void)__hip_atomic_exchange(p, v, __ATOMIC_RELAXED, __HIP_MEMORY_SCOPE_AGENT);
}
__device__ __forceinline__ unsigned long long aload64(const unsigned long long* p) {
    return __hip_atomic_load(p, __ATOMIC_RELAXED, __HIP_MEMORY_SCOPE_AGENT);
}
__device__ __forceinline__ void astore64(unsigned long long* p, unsigned long long v) {
    (void)__hip_atomic_exchange(p, v, __ATOMIC_RELAXED, __HIP_MEMORY_SCOPE_AGENT);
}

// Two-level scan over a 2048-bin histogram: largest bucket such that the
// count of entries in buckets >= it reaches kneed. PLAIN-load version —
// only safe when g was produced by a PREVIOUS KERNEL (kernel-boundary
// acquire) so cached loads see fresh data.
__device__ __forceinline__ void walk_plain(const unsigned int* __restrict__ g,
                                           unsigned int kneed_in,
                                           unsigned int& bucket, unsigned int& kneed_out) {
    __shared__ unsigned int chunks[256];
    __shared__ unsigned int res[2];
    int t = threadIdx.x;
    unsigned int s = 0;
#pragma unroll
    for (int i = 0; i < 8; ++i) s += g[t * 8 + i];
    chunks[t] = s;
    __syncthreads();
    if (t == 0) {
        unsigned int cum = 0; int Cc_ = 0;
        for (int ch = 255; ch >= 0; --ch) {
            if (cum + chunks[ch] >= kneed_in) { Cc_ = ch; break; }
            cum += chunks[ch];
        }
        unsigned int bkt = 0, kn = 1;
        for (int i = 7; i >= 0; --i) {
            unsigned int h = g[Cc_ * 8 + i];
            if (cum + h >= kneed_in) { bkt = (unsigned int)(Cc_ * 8 + i); kn = kneed_in - cum; break; }
            cum += h;
        }
        res[0] = bkt; res[1] = kn;
    }
    __syncthreads();
    bucket = res[0]; kneed_out = res[1];
    __syncthreads();
}

// Atomic-load version: for hists written by OTHER BLOCKS within this kernel
// (only a spin barrier in between). Executed by LEADER blocks only.
__device__ __forceinline__ void walk_atomic(const unsigned int* __restrict__ g,
                                            unsigned int kneed_in,
                                            unsigned int& bucket, unsigned int& kneed_out) {
    __shared__ unsigned int chunks[256];
    __shared__ unsigned int res[2];
    int t = threadIdx.x;
    unsigned int s = 0;
#pragma unroll
    for (int i = 0; i < 8; ++i) s += aload(&g[t * 8 + i]);
    chunks[t] = s;
    __syncthreads();
    if (t == 0) {
        unsigned int cum = 0; int Cc_ = 0;
        for (int ch = 255; ch >= 0; --ch) {
            if (cum + chunks[ch] >= kneed_in) { Cc_ = ch; break; }
            cum += chunks[ch];
        }
        unsigned int bkt = 0, kn = 1;
        for (int i = 7; i >= 0; --i) {
            unsigned int h = aload(&g[Cc_ * 8 + i]);
            if (cum + h >= kneed_in) { bkt = (unsigned int)(Cc_ * 8 + i); kn = kneed_in - cum; break; }
            cum += h;
        }
        res[0] = bkt; res[1] = kn;
    }
    __syncthreads();
    bucket = res[0]; kneed_out = res[1];
    __syncthreads();
}

// ---------------------------------------------------------------------------
// K1: pairwise adjacencies with fused per-row stats. 64x64 tile (512 wgs).
__global__ __launch_bounds__(256) void k_pairwise(const float* __restrict__ x,
                                                  double* __restrict__ E,
                                                  double* __restrict__ Ch,
                                                  double* __restrict__ Cc) {
    int b  = blockIdx.z;
    int i0 = blockIdx.y * 64;
    int j0 = blockIdx.x * 64;
    __shared__ double xi[64][65];
    __shared__ double xj[64][65];
    __shared__ double mi[64], ri_[64], si[64];
    __shared__ double mj[64], rj_[64], sj[64];

    int t  = threadIdx.x;
    int r  = t >> 2;
    int cb = (t & 3) * 16;
    const float* xb = x + (size_t)b * N * C;
    {
        const float4* pi = (const float4*)(xb + (size_t)(i0 + r) * C + cb);
        const float4* pj = (const float4*)(xb + (size_t)(j0 + r) * C + cb);
#pragma unroll
        for (int m4 = 0; m4 < 4; ++m4) {
            float4 fi = pi[m4], fj = pj[m4];
            xi[r][cb + 4 * m4 + 0] = (double)fi.x; xi[r][cb + 4 * m4 + 1] = (double)fi.y;
            xi[r][cb + 4 * m4 + 2] = (double)fi.z; xi[r][cb + 4 * m4 + 3] = (double)fi.w;
            xj[r][cb + 4 * m4 + 0] = (double)fj.x; xj[r][cb + 4 * m4 + 1] = (double)fj.y;
            xj[r][cb + 4 * m4 + 2] = (double)fj.z; xj[r][cb + 4 * m4 + 3] = (double)fj.w;
        }
    }
    __syncthreads();

    if (t < 128) {
        int row = t & 63;
        const double (*xs)[65] = (t < 64) ? xi : xj;
        double sum = 0.0, rr = 0.0;
#pragma unroll 8
        for (int c = 0; c < 64; ++c) { double v = xs[row][c]; sum += v; rr = fma(v, v, rr); }
        double m = sum / 64.0;
        double q = 0.0;
#pragma unroll 8
        for (int c = 0; c < 64; ++c) { double w = xs[row][c] - m; q = fma(w, w, q); }
        double sv = 1.0 / sqrt(q);
        if (t < 64) { mi[row] = m; ri_[row] = rr; si[row] = sv; }
        else        { mj[row] = m; rj_[row] = rr; sj[row] = sv; }
    }
    __syncthreads();

    int ty = t >> 4, tx = t & 15;
    double adot[4][4] = {};
    double amax[4][4] = {};
#pragma unroll 8
    for (int c = 0; c < 64; ++c) {
        double ai[4], aj[4];
#pragma unroll
        for (int p = 0; p < 4; ++p) ai[p] = xi[ty + 16 * p][c];
#pragma unroll
        for (int q = 0; q < 4; ++q) aj[q] = xj[tx + 16 * q][c];
#pragma unroll
        for (int p = 0; p < 4; ++p)
#pragma unroll
            for (int q = 0; q < 4; ++q) {
                double d = ai[p] - aj[q];
                amax[p][q] = fmax(amax[p][q], fabs(d));
                adot[p][q] = fma(ai[p], aj[q], adot[p][q]);
            }
    }

#pragma unroll
    for (int p = 0; p < 4; ++p) {
        int li = ty + 16 * p;
        int ii = i0 + li;
        double rri = ri_[li], mmi = mi[li], ssi = si[li];
#pragma unroll
        for (int q = 0; q < 4; ++q) {
            int lj = tx + 16 * q;
            int jj = j0 + lj;
            double dot = adot[p][q];
            double d2  = rri + rj_[lj] - 2.0 * dot;
            double e   = (ii == jj) ? 0.0 : sqrt(fmax(d2, 0.0));
            double cc  = (dot - 64.0 * mmi * mj[lj]) * ssi * sj[lj];
            cc = fmin(1.0, fmax(-1.0, cc));
            size_t idx = (size_t)b * S + (size_t)ii * N + jj;
            E[idx]  = e;
            Ch[idx] = amax[p][q];
            Cc[idx] = cc;
        }
    }
}

// ---------------------------------------------------------------------------
// K2: C = scale * A * B^T (fp64, MFMA). 64x64 tile, LDS double-buffered.
__global__ __launch_bounds__(256) void k_gemm_nt(const double* __restrict__ A,
                                                 const double* __restrict__ Bm,
                                                 double* __restrict__ Cm,
                                                 double scale) {
    int b = blockIdx.z;
    const double* Ab = A  + (size_t)b * S;
    const double* Bb = Bm + (size_t)b * S;
    double*       Cb = Cm + (size_t)b * S;
    int i0 = blockIdx.y * 64, j0 = blockIdx.x * 64;

    __shared__ double At[2][64][33];
    __shared__ double Bt[2][64][33];

    int t    = threadIdx.x;
    int lane = t & 63;
    int w    = t >> 6;
    int wr   = (w >> 1) * 32;
    int wc   = (w & 1) * 32;
    int fm   = lane & 15;
    int fk   = lane >> 4;

    int sr = t >> 2, sc0 = (t & 3) * 8;

    d4 acc00 = {0.0, 0.0, 0.0, 0.0};
    d4 acc01 = acc00, acc10 = acc00, acc11 = acc00;

    const double* ap = Ab + (size_t)(i0 + sr) * N + sc0;
    const double* bp = Bb + (size_t)(j0 + sr) * N + sc0;

    double pa[8], pb[8];
#pragma unroll
    for (int m = 0; m < 8; ++m) { pa[m] = ap[m]; pb[m] = bp[m]; }
#pragma unroll
    for (int m = 0; m < 8; ++m) { At[0][sr][sc0 + m] = pa[m]; Bt[0][sr][sc0 + m] = pb[m]; }
    __syncthreads();

    int cur = 0;
    for (int k0 = 0; k0 < N; k0 += 32) {
        bool has_next = (k0 + 32 < N);
        if (has_next) {
            ap += 32; bp += 32;
#pragma unroll
            for (int m = 0; m < 8; ++m) { pa[m] = ap[m]; pb[m] = bp[m]; }
        }
#pragma unroll
        for (int kq = 0; kq < 8; ++kq) {
            int kk = kq * 4 + fk;
            double a0 = At[cur][wr + fm][kk];
            double a1 = At[cur][wr + 16 + fm][kk];
            double b0 = Bt[cur][wc + fm][kk];
            double b1 = Bt[cur][wc + 16 + fm][kk];
            acc00 = __builtin_amdgcn_mfma_f64_16x16x4f64(a0, b0, acc00, 0, 0, 0);
            acc01 = __builtin_amdgcn_mfma_f64_16x16x4f64(a0, b1, acc01, 0, 0, 0);
            acc10 = __builtin_amdgcn_mfma_f64_16x16x4f64(a1, b0, acc10, 0, 0, 0);
            acc11 = __builtin_amdgcn_mfma_f64_16x16x4f64(a1, b1, acc11, 0, 0, 0);
        }
        if (has_next) {
            int nxt = cur ^ 1;
#pragma unroll
            for (int m = 0; m < 8; ++m) { At[nxt][sr][sc0 + m] = pa[m]; Bt[nxt][sr][sc0 + m] = pb[m]; }
            __syncthreads();
            cur = nxt;
        }
    }
    int r0 = i0 + wr + 4 * fk;
    int c0 = j0 + wc + fm;
#pragma unroll
    for (int r = 0; r < 4; ++r) {
        Cb[(size_t)(r0 + r)      * N + c0]      = acc00[r] * scale;
        Cb[(size_t)(r0 + r)      * N + c0 + 16] = acc01[r] * scale;
        Cb[(size_t)(r0 + 16 + r) * N + c0]      = acc10[r] * scale;
        Cb[(size_t)(r0 + 16 + r) * N + c0 + 16] = acc11[r] * scale;
    }
}

// ---------------------------------------------------------------------------
// K4: W = A * B (fp64, MFMA) + key32 epilogue + FUSED hist0 (bins key>>21).
__global__ __launch_bounds__(256) void k_gemm_nn(const double* __restrict__ A,
                                                 const double* __restrict__ Bm,
                                                 double* __restrict__ Wm,
                                                 unsigned int* __restrict__ kq_out,
                                                 unsigned int* __restrict__ g0) {
    int b = blockIdx.z;
    const double* Ab = A  + (size_t)b * S;
    const double* Bb = Bm + (size_t)b * S;
    double*       Wb = Wm + (size_t)b * S;
    unsigned int* kb = kq_out + (size_t)b * S;
    int i0 = blockIdx.y * 64, j0 = blockIdx.x * 64;

    __shared__ double At[2][64][33];
    __shared__ double Bt[2][32][65];
    __shared__ unsigned int h0[2048];

    int t    = threadIdx.x;
    int lane = t & 63;
    int w    = t >> 6;
    int wr   = (w >> 1) * 32;
    int wc   = (w & 1) * 32;
    int fm   = lane & 15;
    int fk   = lane >> 4;

    int sr = t >> 2, sc0 = (t & 3) * 8;   // A staging: 64 rows x 32 k
    int br = t >> 3, bc = (t & 7) * 8;    // B staging: 32 k x 64 cols

    for (int i = t; i < 2048; i += 256) h0[i] = 0u;

    d4 acc00 = {0.0, 0.0, 0.0, 0.0};
    d4 acc01 = acc00, acc10 = acc00, acc11 = acc00;

    const double* ap = Ab + (size_t)(i0 + sr) * N + sc0;
    const double* bp = Bb + (size_t)br * N + j0 + bc;

    double pa[8], pb[8];
#pragma unroll
    for (int m = 0; m < 8; ++m) { pa[m] = ap[m]; pb[m] = bp[m]; }
#pragma unroll
    for (int m = 0; m < 8; ++m) { At[0][sr][sc0 + m] = pa[m]; Bt[0][br][bc + m] = pb[m]; }
    __syncthreads();

    int cur = 0;
    for (int k0 = 0; k0 < N; k0 += 32) {
        bool has_next = (k0 + 32 < N);
        if (has_next) {
            ap += 32; bp += (size_t)32 * N;
#pragma unroll
            for (int m = 0; m < 8; ++m) { pa[m] = ap[m]; pb[m] = bp[m]; }
        }
#pragma unroll
        for (int kq = 0; kq < 8; ++kq) {
            int kk = kq * 4 + fk;
            double a0 = At[cur][wr + fm][kk];
            double a1 = At[cur][wr + 16 + fm][kk];
            double b0 = Bt[cur][kk][wc + fm];
            double b1 = Bt[cur][kk][wc + 16 + fm];
            acc00 = __builtin_amdgcn_mfma_f64_16x16x4f64(a0, b0, acc00, 0, 0, 0);
            acc01 = __builtin_amdgcn_mfma_f64_16x16x4f64(a0, b1, acc01, 0, 0, 0);
            acc10 = __builtin_amdgcn_mfma_f64_16x16x4f64(a1, b0, acc10, 0, 0, 0);
            acc11 = __builtin_amdgcn_mfma_f64_16x16x4f64(a1, b1, acc11, 0, 0, 0);
        }
        if (has_next) {
            int nxt = cur ^ 1;
#pragma unroll
            for (int m = 0; m < 8; ++m) { At[nxt][sr][sc0 + m] = pa[m]; Bt[nxt][br][bc + m] = pb[m]; }
            __syncthreads();
            cur = nxt;
        }
    }
    int r0 = i0 + wr + 4 * fk;
    int c0 = j0 + wc + fm;
#pragma unroll
    for (int r = 0; r < 4; ++r) {
        double w00 = acc00[r], w01 = acc01[r], w10 = acc10[r], w11 = acc11[r];
        size_t i00 = (size_t)(r0 + r)      * N + c0;
        size_t i01 = (size_t)(r0 + r)      * N + c0 + 16;
        size_t i10 = (size_t)(r0 + 16 + r) * N + c0;
        size_t i11 = (size_t)(r0 + 16 + r) * N + c0 + 16;
        unsigned int k00 = (unsigned int)(d2key(w00) >> 32);
        unsigned int k01 = (unsigned int)(d2key(w01) >> 32);
        unsigned int k10 = (unsigned int)(d2key(w10) >> 32);
        unsigned int k11 = (unsigned int)(d2key(w11) >> 32);
        Wb[i00] = w00; kb[i00] = k00;
        Wb[i01] = w01; kb[i01] = k01;
        Wb[i10] = w10; kb[i10] = k10;
        Wb[i11] = w11; kb[i11] = k11;
        atomicAdd(&h0[k00 >> 21], 1u);
        atomicAdd(&h0[k01 >> 21], 1u);
        atomicAdd(&h0[k10 >> 21], 1u);
        atomicAdd(&h0[k11 >> 21], 1u);
    }
    __syncthreads();
    unsigned int* g = g0 + b * 2048;
    for (int i = t; i < 2048; i += 256)
        if (h0[i]) __hip_atomic_fetch_add(&g[i], h0[i], __ATOMIC_RELAXED,
                                          __HIP_MEMORY_SCOPE_AGENT);
}

// ---------------------------------------------------------------------------
// K3: fp64 row softmax. Wave per row, shuffle-only; 512 wgs.
__global__ __launch_bounds__(256) void k_softmax(double* __restrict__ L) {
    int row = (blockIdx.x << 2) + (threadIdx.x >> 6);
    int ln  = threadIdx.x & 63;
    double* p = L + (size_t)row * N;

    double v[16];
#pragma unroll
    for (int q = 0; q < 16; ++q) v[q] = p[ln + 64 * q];

    double mx = v[0];
#pragma unroll
    for (int q = 1; q < 16; ++q) mx = fmax(mx, v[q]);
#pragma unroll
    for (int off = 32; off >= 1; off >>= 1) mx = fmax(mx, __shfl_xor(mx, off));

    double s = 0.0;
#pragma unroll
    for (int q = 0; q < 16; ++q) { v[q] = exp(v[q] - mx); s += v[q]; }
#pragma unroll
    for (int off = 32; off >= 1; off >>= 1) s += __shfl_xor(s, off);

#pragma unroll
    for (int q = 0; q < 16; ++q) p[ln + 64 * q] = v[q] / s;
}

// ---------------------------------------------------------------------------
// K5: fused selection, 2 full passes + 2 grid barriers. All-block redundant
// work now uses PLAIN (cacheable) loads; atomic loads confined to leader
// blocks and single-line polls.
__device__ __forceinline__ void gridbar(unsigned int* bar, unsigned int* phase) {
    asm volatile("s_waitcnt vmcnt(0)" ::: "memory");
    __syncthreads();
    if (threadIdx.x == 0) {
        unsigned int ph = ++(*phase);
        int g = (int)(blockIdx.x >> 4);
        unsigned int a1 = __hip_atomic_fetch_add(&bar[32 + g * 16], 1u,
                              __ATOMIC_RELAXED, __HIP_MEMORY_SCOPE_AGENT) + 1u;
        if (a1 == ph * 16u) {
            unsigned int a2 = __hip_atomic_fetch_add(&bar[0], 1u,
                                  __ATOMIC_RELAXED, __HIP_MEMORY_SCOPE_AGENT) + 1u;
            if (a2 == ph * 16u) astore(&bar[16], ph);
        }
        while (aload(&bar[16]) < ph) __builtin_amdgcn_s_sleep(4);
        asm volatile("" ::: "memory");
    }
    __syncthreads();
}

__global__ __launch_bounds__(256) void k_select(const unsigned int* __restrict__ key32,
                                                const double* __restrict__ W,
                                                const unsigned int* __restrict__ g0,
                                                unsigned int* __restrict__ g1,
                                                unsigned int* __restrict__ cnt,
                                                unsigned long long* __restrict__ cand,
                                                unsigned long long* __restrict__ pub,
                                                unsigned int* __restrict__ bar,
                                                float* __restrict__ out) {
    int blk = blockIdx.x, t = threadIdx.x;
    int b = blk >> 7, lb = blk & 127;
    int lane = t & 63;
    unsigned int phase = 0;

    __shared__ unsigned int lh[2048];
    __shared__ unsigned long long s_p64;
    __shared__ unsigned int s_kk;

    const uint4* k4 = (const uint4*)(key32 + (size_t)b * S + (size_t)lb * 8192);

    // ---- phase 1: walk g0 (PLAIN loads — prior-kernel data), hist mid-11 ----
    unsigned int B0, kn1;
    walk_plain(g0 + b * 2048, (unsigned int)KSEL, B0, kn1);
    for (int i = t; i < 2048; i += 256) lh[i] = 0;
    __syncthreads();
#pragma unroll
    for (int it = 0; it < 8; ++it) {
        uint4 kv = k4[it * 256 + t];
        unsigned int ks[4] = {kv.x, kv.y, kv.z, kv.w};
#pragma unroll
        for (int c = 0; c < 4; ++c)
            if ((ks[c] >> 21) == B0) atomicAdd(&lh[(ks[c] >> 10) & 0x7FFu], 1u);
    }
    __syncthreads();
    for (int i = t; i < 2048; i += 256)
        if (lh[i]) __hip_atomic_fetch_add(&g1[b * 2048 + i], lh[i], __ATOMIC_RELAXED,
                                          __HIP_MEMORY_SCOPE_AGENT);
    gridbar(bar, &phase);

    // ---- phase 2a: LEADER-only walk of g1 (atomic loads), publish B1/kn2 ----
    if (lb == 0) {
        unsigned int B1l, kn2l;
        walk_atomic(g1 + b * 2048, kn1, B1l, kn2l);
        if (t == 0) {
            unsigned long long v = (1ULL << 63) |
                                   (((unsigned long long)B1l) << 32) |
                                   (unsigned long long)kn2l;
            astore64(&pub[b * 16], v);
            s_p64 = v;
        }
        __syncthreads();
    } else {
        if (t == 0) {
            unsigned long long v;
            while (((v = aload64(&pub[b * 16])) >> 63) == 0ULL)
                __builtin_amdgcn_s_sleep(4);
            s_p64 = v;
        }
        __syncthreads();
    }
    unsigned int B1  = (unsigned int)((s_p64 >> 32) & 0x7FFULL);
    unsigned int kn2 = (unsigned int)(s_p64 & 0xFFFFFFFFULL);
    __syncthreads();
    unsigned int pref22 = (B0 << 11) | B1;

    // ---- phase 2b: mask for non-ties + tie collection ----
    unsigned long long lmask = (1ULL << lane) - 1ULL;
    unsigned long long* cb = cand + (size_t)b * EQCAP;
    const double* Wb = W + (size_t)b * S;
    float4* ob = (float4*)(out + (size_t)b * S + (size_t)lb * 8192);
#pragma unroll
    for (int it = 0; it < 8; ++it) {
        uint4 kv = k4[it * 256 + t];
        unsigned int ks[4] = {kv.x, kv.y, kv.z, kv.w};
        float ov[4];
#pragma unroll
        for (int c = 0; c < 4; ++c) {
            unsigned int k = ks[c];
            unsigned int t22 = k >> 10;
            bool m = (t22 == pref22);
            unsigned long long mb = __ballot(m);
            ov[c] = (t22 > pref22) ? 1.0f : 0.0f;   // ties: placeholder, fixed in 3b
            if (mb != 0ULL) {
                int ldr = __ffsll((long long)mb) - 1;
                unsigned int base = 0;
                if (lane == ldr)
                    base = __hip_atomic_fetch_add(&cnt[b * 16], (unsigned int)__popcll(mb),
                                                  __ATOMIC_RELAXED, __HIP_MEMORY_SCOPE_AGENT);
                base = __shfl(base, ldr, 64);
                if (m) {
                    unsigned int pos = base + (unsigned int)__popcll(mb & lmask);
                    if (pos < (unsigned int)EQCAP) {
                        int s = lb * 8192 + it * 1024 + t * 4 + c;
                        unsigned long long full = d2key(Wb[s]);
                        unsigned long long packed =
                            (((unsigned long long)(k & 0x3FFu)) << 52) |
                            ((full & 0xFFFFFFFFULL) << 20) |
                            (unsigned long long)(unsigned int)s;
                        astore64(&cb[pos], packed);
                    }
                }
            }
        }
        ob[it * 256 + t] = make_float4(ov[0], ov[1], ov[2], ov[3]);
    }
    gridbar(bar, &phase);

    // ---- phase 3a: leader radix-selects packed cutoff (PLAIN cand loads —
    //      cand was written only via coherence-point exchanges, so no cached
    //      copies exist anywhere; plain post-barrier loads are fresh) ----
    if (lb == 0) {
        unsigned int c_ = aload(&cnt[b * 16]);
        if (c_ > (unsigned int)EQCAP) c_ = EQCAP;
        unsigned long long rpref = 0ULL;
        unsigned int rk = kn2;
#pragma unroll 1
        for (int pass = 0; pass < 8; ++pass) {
            int shift = 56 - 8 * pass;
            lh[t] = 0;
            __syncthreads();
            for (unsigned int e = t; e < c_; e += 256) {
                unsigned long long p = cb[e];
                bool match = (pass == 0) || ((p >> (shift + 8)) == (rpref >> (shift + 8)));
                if (match) atomicAdd(&lh[(unsigned int)((p >> shift) & 255ULL)], 1u);
            }
            __syncthreads();
            if (t == 0) {
                unsigned int cum = 0; int bucket = 0;
                for (int i = 255; i >= 0; --i) {
                    unsigned int h = lh[i];
                    if (cum + h >= rk) { bucket = i; break; }
                    cum += h;
                }
                s_p64 = rpref | (((unsigned long long)bucket) << shift);
                s_kk  = rk - cum;
            }
            __syncthreads();
            rpref = s_p64; rk = s_kk;
            __syncthreads();
        }
        if (t == 0) astore64(&pub[b * 16 + 8], (1ULL << 63) | rpref);
    }

    // ---- phase 3b: every block fixes up its OWN tile's ties ----
    if (t == 0) {
        unsigned long long v;
        while (((v = aload64(&pub[b * 16 + 8])) >> 63) == 0ULL)
            __builtin_amdgcn_s_sleep(4);
        s_p64 = v;
    }
    __syncthreads();
    unsigned long long Ccut = s_p64 & 0x7FFFFFFFFFFFFFFFULL;

    float* outb = out + (size_t)b * S;
#pragma unroll
    for (int it = 0; it < 8; ++it) {
        uint4 kv = k4[it * 256 + t];
        unsigned int ks[4] = {kv.x, kv.y, kv.z, kv.w};
#pragma unroll
        for (int c = 0; c < 4; ++c) {
            unsigned int k = ks[c];
            if ((k >> 10) == pref22) {
                int s = lb * 8192 + it * 1024 + t * 4 + c;
                unsigned long long full = d2key(Wb[s]);
                unsigned long long packed =
                    (((unsigned long long)(k & 0x3FFu)) << 52) |
                    ((full & 0xFFFFFFFFULL) << 20) |
                    (unsigned long long)(unsigned int)s;
                outb[s] = (packed >= Ccut) ? 1.0f : 0.0f;   // same thread wrote
            }                                               // the placeholder
        }
    }
}

// ---------------------------------------------------------------------------
extern "C" void kernel_launch(void* const* d_in, const int* in_sizes, int n_in,
                              void* d_out, int out_size, void* d_ws, size_t ws_size,
                              hipStream_t stream) {
    const float* x = (const float*)d_in[0];
    float* out = (float*)d_out;

    char* ws = (char*)d_ws;
    size_t off = 0;
    auto alloc = [&](size_t bytes) -> void* {
        void* p = ws + off;
        off += (bytes + 255) & ~(size_t)255;
        return p;
    };

    double* E     = (double*)alloc((size_t)BB * S * sizeof(double));       // 16 MB
    double* Ch    = (double*)alloc((size_t)BB * S * sizeof(double));       // 16 MB
    double* Cc    = (double*)alloc((size_t)BB * S * sizeof(double));       // 16 MB
    double* L     = (double*)alloc((size_t)BB * S * sizeof(double));       // 16 MB
    unsigned int* key32 = (unsigned int*)alloc((size_t)BB * S * sizeof(unsigned int)); // 8 MB
    double* W     = E;  // E dead after gemm_nt -> reuse for weighted

    // selection scratch (one contiguous memset region)
    // layout (u32): g0[4096] g1[4096] cnt[32] bar[512] pub[64 u64 -> 128 u32]
    unsigned int* selz = (unsigned int*)alloc((4096 + 4096 + 32 + 512 + 128) * sizeof(unsigned int));
    unsigned int* g0   = selz;
    unsigned int* g1   = selz + 4096;
    unsigned int* cnt  = selz + 8192;
    unsigned int* bar  = selz + 8224;
    unsigned long long* pub = (unsigned long long*)(selz + 8736);   // [2][16] u64
    unsigned long long* cand =
        (unsigned long long*)alloc((size_t)BB * EQCAP * sizeof(unsigned long long)); // 16 MB

    // 0) zero selection scratch
    hipMemsetAsync(selz, 0, (4096 + 4096 + 32 + 512 + 128) * sizeof(unsigned int), stream);

    // 1) pairwise adjacencies (fused per-row stats)
    k_pairwise<<<dim3(N / 64, N / 64, BB), 256, 0, stream>>>(x, E, Ch, Cc);

    // 2) logits = (E @ Ch^T) * 1/8
    k_gemm_nt<<<dim3(N / 64, N / 64, BB), 256, 0, stream>>>(E, Ch, L, 0.125);

    // 3) softmax rows
    k_softmax<<<512, 256, 0, stream>>>(L);

    // 4) weighted = attn @ Cc + key32 epilogue + fused hist0
    k_gemm_nn<<<dim3(N / 64, N / 64, BB), 256, 0, stream>>>(L, Cc, W, key32, g0);

    // 5) fused selection (2 full passes, leader-only atomic walks)
    k_select<<<NSELBLK, 256, 0, stream>>>(key32, W, g0, g1, cnt, cand, pub, bar, out);
}